// Round 4
// baseline (135.436 us; speedup 1.0000x reference)
//
#include <hip/hip_runtime.h>
#include <cmath>

// Noisy 8-qubit density-matrix sim, batch 32, depth 6 — 4-pass, 6-qubit-window,
// 512-thread blocks: each 16-el stage group is split across a thread PAIR (on the
// row-target bit b). 8 els/thread -> 4096 waves -> 4 waves/SIMD (was 2).
// Cross coupling (target-wire noise t00<->t11) handled by re-reading the partner's
// 4-el column from LDS and re-applying the 16-flop control-wire noise (wave-lockstep
// => race-free). R7 stages (dense on (b,d)) duplicate full-16 compute per pair.

typedef float2 cplx;

#define BATCH 32
#define DEPTH 6

__device__ __forceinline__ cplx cmul(cplx a, cplx b){
  return make_float2(a.x*b.x - a.y*b.y, a.x*b.y + a.y*b.x);
}
__device__ __forceinline__ cplx cadd(cplx a, cplx b){ return make_float2(a.x+b.x, a.y+b.y); }
__device__ __forceinline__ cplx cscale(float s, cplx a){ return make_float2(s*a.x, s*a.y); }

struct N1C { float A,B,C,D,E; };
__device__ __forceinline__ N1C noise_coeffs(float g){
  float ga = g*0.3f, gp = g*0.2f, p = g*0.5f;
  N1C n;
  n.A = 1.0f - 2.0f*p/3.0f;
  n.D = 2.0f*p/3.0f;
  n.B = ga*n.A + n.D*(1.0f-ga);
  n.E = n.D*ga + n.A*(1.0f-ga);
  n.C = (1.0f - 4.0f*p/3.0f) * sqrtf(1.0f-ga) * sqrtf(1.0f-gp);
  return n;
}

// swizzle: phys = L ^ rot-left-3(row-local)
__device__ __forceinline__ int physof(int L){
  int rl = L >> 6;
  int rot = ((rl<<3)|(rl>>3)) & 63;
  return L ^ rot;
}
__device__ __forceinline__ constexpr int KPc(int p){
  return (p < 6) ? (1<<p) : ((1<<p) | (1 << (((p-6)+3)%6)));
}

// per-stage group-bit -> free-logical-position tables.
// Effective bank-pair bit of position p: c(p) = p<6 ? p : (p-3)%6.
// Lane = (g&31)<<1 | bsel ; bsel's addr bit is position 5+U (c=(U+2)%6).
// Rows chosen so lane bits cover pair-bits {0,1,2,3} exactly -> uniform 4 lanes/pair.
template<int U>
__device__ __forceinline__ int base_for(int g){
  constexpr int P[6][8] = {
    {0,0,0,0,0,0,0,0},
    {9,10,2,4,5, 3,8,11},   // u=1 (active {0,1,6,7};  bsel->c3)
    {0,10,11,3,5, 4,6,9},   // u=2 (active {1,2,7,8};  bsel->c4)
    {0,1,11,6,4, 5,7,10},   // u=3 (active {2,3,8,9};  bsel->c5)
    {1,2,6,7,5, 0,8,11},    // u=4 (active {3,4,9,10}; bsel->c0)
    {0,2,3,7,8, 1,6,9}};    // u=5 (active {4,5,10,11};bsel->c1)
  int b = 0;
  #pragma unroll
  for (int i=0;i<8;i++) b ^= (-((g>>i)&1)) & KPc(P[U][i]);
  return b;
}

// ---------------- prep ----------------
__global__ __launch_bounds__(256) void prep_kernel(const float* __restrict__ x,
                                                   const float* __restrict__ w,
                                                   cplx* __restrict__ S1,
                                                   float* __restrict__ m){
  int t = threadIdx.x;
  N1C n1 = noise_coeffs(0.0003f);
  if (t < DEPTH*8){
    int l = t >> 3, i = t & 7;
    float w0 = w[(l*8+i)*2 + 0];
    float w1 = w[(l*8+i)*2 + 1];
    float c = cosf(0.5f*w0), s = sinf(0.5f*w0);
    float U[2][2] = {{c,-s},{s,c}};
    cplx ph01 = make_float2(cosf(w1), -sinf(w1));
    cplx ph10 = make_float2(ph01.x, -ph01.y);
    cplx* S = S1 + t*16;
    #pragma unroll
    for (int a=0;a<2;a++)
      #pragma unroll
      for (int b=0;b<2;b++){
        int k = 2*a+b;
        float u0a=U[0][a], u0b=U[0][b], u1a=U[1][a], u1b=U[1][b];
        S[0*4+k] = make_float2(n1.A*u0a*u0b + n1.B*u1a*u1b, 0.f);
        S[1*4+k] = cscale(n1.C*u0a*u1b, ph01);
        S[2*4+k] = cscale(n1.C*u1a*u0b, ph10);
        S[3*4+k] = make_float2(n1.D*u0a*u0b + n1.E*u1a*u1b, 0.f);
      }
  }
  {
    int b = t >> 3, i = t & 7;
    float xv = x[b*8+i];
    float c = cosf(0.5f*xv), s = sinf(0.5f*xv);
    float p00=c*c, p01=c*s, p11=s*s;
    float* mm = m + t*4;
    mm[0] = n1.A*p00 + n1.B*p11;
    mm[1] = n1.C*p01;
    mm[2] = n1.C*p01;
    mm[3] = n1.D*p00 + n1.E*p11;
  }
}

// ---------------- half-stage: thread owns b=bsel half of a 16-group ----------------
// local idx i = a<<2 | cc<<1 | d
template<int U>
__device__ __forceinline__ void do_stage_half(cplx* slab, const cplx* __restrict__ S,
                                              int bp, int bsel, N1C n2,
                                              float al, float be, float ga, float de){
  constexpr int KA = KPc(6+U), KB = KPc(5+U), KC = 1<<U, KD = 1<<(U-1);
  int bb = bsel ? KB : 0;
  int nb = bsel ^ 1;
  int xn = (nb ? KB : 0) ^ (nb ? KD : 0);
  cplx h[8], X[4];
  #pragma unroll
  for (int i=0;i<8;i++){
    int a=(i>>2)&1, cc=(i>>1)&1, d=i&1;
    int pos = bp ^ bb ^ (a?(KA^KB):0) ^ (cc?(KC^KD):0) ^ (d?KD:0);
    h[i] = slab[pos];
  }
  #pragma unroll
  for (int j=0;j<4;j++){
    int a=j>>1, cc=j&1;
    int pos = bp ^ xn ^ (a?(KA^KB):0) ^ (cc?(KC^KD):0);
    X[j] = slab[pos];
  }
  // control-wire noise on own els (per d) : (a,cc) in {0..3} -> idx j<<1|d
  #pragma unroll
  for (int d=0;d<2;d++){
    cplx t00=h[0|d], t01=h[2|d], t10=h[4|d], t11=h[6|d];
    h[0|d] = cadd(cscale(n2.A,t00), cscale(n2.B,t11));
    h[2|d] = cscale(n2.C,t01);
    h[4|d] = cscale(n2.C,t10);
    h[6|d] = cadd(cscale(n2.D,t00), cscale(n2.E,t11));
  }
  // control-wire noise on partner column
  {
    cplx e00=X[0], e01=X[1], e10=X[2], e11=X[3];
    X[0] = cadd(cscale(n2.A,e00), cscale(n2.B,e11));
    X[1] = cscale(n2.C,e01);
    X[2] = cscale(n2.C,e10);
    X[3] = cadd(cscale(n2.D,e00), cscale(n2.E,e11));
  }
  // target-wire noise (coefficients pre-selected by bsel)
  #pragma unroll
  for (int j=0;j<4;j++){
    h[2*j]   = cadd(cscale(al,h[2*j]),   cscale(be,X[j]));
    h[2*j+1] = cadd(cscale(ga,h[2*j+1]), cscale(de,X[j]));
  }
  // R(control): dense 4x4 on (a,cc) per d
  #pragma unroll
  for (int d=0;d<2;d++){
    cplx v0=h[0|d], v1=h[2|d], v2=h[4|d], v3=h[6|d];
    h[0|d] = cadd(cadd(cmul(S[0],v0),  cmul(S[1],v1)),  cadd(cmul(S[2],v2),  cmul(S[3],v3)));
    h[2|d] = cadd(cadd(cmul(S[4],v0),  cmul(S[5],v1)),  cadd(cmul(S[6],v2),  cmul(S[7],v3)));
    h[4|d] = cadd(cadd(cmul(S[8],v0),  cmul(S[9],v1)),  cadd(cmul(S[10],v2), cmul(S[11],v3)));
    h[6|d] = cadd(cadd(cmul(S[12],v0), cmul(S[13],v1)), cadd(cmul(S[14],v2), cmul(S[15],v3)));
  }
  #pragma unroll
  for (int i=0;i<8;i++){
    int a=(i>>2)&1, cc=(i>>1)&1, d=i&1;
    int pos = bp ^ bb ^ (a?KA:0) ^ (cc?KC:0) ^ (d?KD:0);
    slab[pos] = h[i];
  }
}

// ---------------- R7 stage: full-16 compute per pair, write own half ----------------
template<int U>
__device__ __forceinline__ void do_stage_r7(cplx* slab, const cplx* __restrict__ S,
                                            const cplx* __restrict__ S7,
                                            int bp, int bsel, N1C n2){
  constexpr int KA = KPc(6+U), KB = KPc(5+U), KC = 1<<U, KD = 1<<(U-1);
  cplx h[16];
  #pragma unroll
  for (int idx=0; idx<16; idx++){
    int a=(idx>>3)&1, b=(idx>>2)&1, cc=(idx>>1)&1, d=idx&1;
    int pos = bp ^ (a?KA:0) ^ ((b^a)?KB:0) ^ (cc?KC:0) ^ ((d^cc)?KD:0);
    h[idx] = slab[pos];
  }
  #pragma unroll
  for (int b=0;b<2;b++)
    #pragma unroll
    for (int d=0;d<2;d++){
      int i00 = (b<<2)|d;
      cplx t00=h[i00], t01=h[i00|2], t10=h[i00|8], t11=h[i00|10];
      h[i00]    = cadd(cscale(n2.A,t00), cscale(n2.B,t11));
      h[i00|2]  = cscale(n2.C, t01);
      h[i00|8]  = cscale(n2.C, t10);
      h[i00|10] = cadd(cscale(n2.D,t00), cscale(n2.E,t11));
    }
  #pragma unroll
  for (int a=0;a<2;a++)
    #pragma unroll
    for (int cc=0;cc<2;cc++){
      int i00 = (a<<3)|(cc<<1);
      cplx t00=h[i00], t01=h[i00|1], t10=h[i00|4], t11=h[i00|5];
      h[i00]   = cadd(cscale(n2.A,t00), cscale(n2.B,t11));
      h[i00|1] = cscale(n2.C, t01);
      h[i00|4] = cscale(n2.C, t10);
      h[i00|5] = cadd(cscale(n2.D,t00), cscale(n2.E,t11));
    }
  #pragma unroll
  for (int b=0;b<2;b++)
    #pragma unroll
    for (int d=0;d<2;d++){
      int i0 = (b<<2)|d;
      cplx v0=h[i0], v1=h[i0|2], v2=h[i0|8], v3=h[i0|10];
      h[i0]    = cadd(cadd(cmul(S[0],v0),  cmul(S[1],v1)),  cadd(cmul(S[2],v2),  cmul(S[3],v3)));
      h[i0|2]  = cadd(cadd(cmul(S[4],v0),  cmul(S[5],v1)),  cadd(cmul(S[6],v2),  cmul(S[7],v3)));
      h[i0|8]  = cadd(cadd(cmul(S[8],v0),  cmul(S[9],v1)),  cadd(cmul(S[10],v2), cmul(S[11],v3)));
      h[i0|10] = cadd(cadd(cmul(S[12],v0), cmul(S[13],v1)), cadd(cmul(S[14],v2), cmul(S[15],v3)));
    }
  #pragma unroll
  for (int a=0;a<2;a++)
    #pragma unroll
    for (int cc=0;cc<2;cc++){
      int i0 = (a<<3)|(cc<<1);
      cplx v0=h[i0], v1=h[i0|1], v2=h[i0|4], v3=h[i0|5];
      h[i0]   = cadd(cadd(cmul(S7[0],v0),  cmul(S7[1],v1)),  cadd(cmul(S7[2],v2),  cmul(S7[3],v3)));
      h[i0|1] = cadd(cadd(cmul(S7[4],v0),  cmul(S7[5],v1)),  cadd(cmul(S7[6],v2),  cmul(S7[7],v3)));
      h[i0|4] = cadd(cadd(cmul(S7[8],v0),  cmul(S7[9],v1)),  cadd(cmul(S7[10],v2), cmul(S7[11],v3)));
      h[i0|5] = cadd(cadd(cmul(S7[12],v0), cmul(S7[13],v1)), cadd(cmul(S7[14],v2), cmul(S7[15],v3)));
    }
  #pragma unroll
  for (int idx=0; idx<16; idx++){
    int a=(idx>>3)&1, b=(idx>>2)&1, cc=(idx>>1)&1, d=idx&1;
    if (b == bsel){
      int pos = bp ^ (a?KA:0) ^ (b?KB:0) ^ (cc?KC:0) ^ (d?KD:0);
      slab[pos] = h[idx];
    }
  }
}

#define STG(l,q,u)  do_stage_half<u>(slab, sS+((l)*8+(q))*16, base_for<u>(gg), bsel, n2, al,be,ga,de); __syncthreads();
#define STG7(l,q,u) do_stage_r7<u>(slab, sS+((l)*8+(q))*16, sS+((l)*8+7)*16, base_for<u>(gg), bsel, n2); __syncthreads();

#define THREAD_SPLIT \
  int t = threadIdx.x; int bsel = t & 1; int gg = t >> 1; \
  N1C n2 = noise_coeffs(0.0065f); \
  float al = bsel ? n2.C : n2.A; \
  float be = bsel ? 0.f  : n2.B; \
  float ga = bsel ? n2.E : n2.C; \
  float de = bsel ? n2.D : 0.f;

// ---------------- pass A: window qubits 0..5, outer = qubit 6,7 bits ----------------
__global__ __launch_bounds__(512,4) void passA_kernel(const cplx* __restrict__ S1,
                                                      const float* __restrict__ m,
                                                      cplx* __restrict__ gout){
  __shared__ cplx slab[4096];
  __shared__ cplx sS[768];
  __shared__ float sm[32];
  THREAD_SPLIT
  int s = blockIdx.x >> 4, oA = blockIdx.x & 15;
  for (int i=t;i<768;i+=512) sS[i]=S1[i];
  if (t<32) sm[t]=m[s*32+t];
  __syncthreads();
  int oAr=oA>>2, oAc=oA&3;
  float m67 = sm[24+(oAr>>1)*2+(oAc>>1)] * sm[28+(oAr&1)*2+(oAc&1)];
  #pragma unroll
  for (int k=0;k<8;k++){
    int L=(k<<9)|t, rl=L>>6, cl=L&63;
    float v=m67;
    #pragma unroll
    for (int i=0;i<6;i++) v *= sm[i*4+((rl>>(5-i))&1)*2+((cl>>(5-i))&1)];
    slab[physof(L)]=make_float2(v,0.f);
  }
  __syncthreads();
  STG(0,0,5) STG(0,1,4) STG(0,2,3) STG(0,3,2) STG(0,4,1)
  STG(1,0,5) STG(1,1,4) STG(1,2,3) STG(1,3,2)
  STG(2,0,5) STG(2,1,4) STG(2,2,3)
  STG(3,0,5) STG(3,1,4)
  STG(4,0,5)
  cplx* g = gout + (size_t)s*65536 + oA*4096;
  #pragma unroll
  for (int k=0;k<8;k++){ int L=(k<<9)|t; g[L]=slab[physof(L)]; }
}

// ---------------- pass B: window qubits 2..7, outer = qubit 0,1 bits ----------------
__global__ __launch_bounds__(512,4) void passB_kernel(const cplx* __restrict__ S1,
                                                      const cplx* __restrict__ gin,
                                                      cplx* __restrict__ gout){
  __shared__ cplx slab[4096];
  __shared__ cplx sS[768];
  THREAD_SPLIT
  int s=blockIdx.x>>4, oB=blockIdx.x&15;
  int r67=oB>>2, c67=oB&3;
  for (int i=t;i<768;i+=512) sS[i]=S1[i];
  const cplx* g = gin + (size_t)s*65536;
  #pragma unroll
  for (int j=0;j<8;j++){
    int f = (j<<9)|t, mI = f>>8, told = f&255;
    cplx v = g[mI*4096 + (((r67<<4)|(told>>4))<<6) + ((c67<<4)|(told&15))];
    int rlB = ((told>>4)<<2)|(mI>>2);
    int clB = ((told&15)<<2)|(mI&3);
    slab[physof((rlB<<6)|clB)] = v;
  }
  __syncthreads();
  STG(0,5,2) STG7(0,6,1)
  STG(1,4,3) STG(1,5,2) STG7(1,6,1)
  STG(2,3,4) STG(2,4,3) STG(2,5,2) STG7(2,6,1)
  STG(3,2,5) STG(3,3,4) STG(3,4,3) STG(3,5,2) STG7(3,6,1)
  cplx* go = gout + (size_t)s*65536 + oB*4096;
  #pragma unroll
  for (int k=0;k<8;k++){ int L=(k<<9)|t; go[L]=slab[physof(L)]; }
}

// ---------------- pass C: window qubits 0..5, reads pass-B layout ----------------
__global__ __launch_bounds__(512,4) void passC_kernel(const cplx* __restrict__ S1,
                                                      const cplx* __restrict__ gin,
                                                      cplx* __restrict__ gout){
  __shared__ cplx slab[4096];
  __shared__ cplx sS[768];
  THREAD_SPLIT
  int s=blockIdx.x>>4, oC=blockIdx.x&15;
  int oCr=oC>>2, oCc=oC&3;
  for (int i=t;i<768;i+=512) sS[i]=S1[i];
  const cplx* g = gin + (size_t)s*65536;
  #pragma unroll
  for (int j=0;j<8;j++){
    int f = (j<<9)|t, mI = f>>8, told = f&255;
    int xx=told>>4, y=told&15;
    cplx v = g[mI*4096 + (((xx<<2)|oCr)<<6) + ((y<<2)|oCc)];
    int rlC = ((mI>>2)<<4)|xx;
    int clC = ((mI&3)<<4)|y;
    slab[physof((rlC<<6)|clC)] = v;
  }
  __syncthreads();
  STG(4,1,4) STG(4,2,3) STG(4,3,2) STG(4,4,1)
  STG(5,0,5) STG(5,1,4) STG(5,2,3) STG(5,3,2)
  cplx* go = gout + (size_t)s*65536 + oC*4096;
  #pragma unroll
  for (int k=0;k<8;k++){ int L=(k<<9)|t; go[L]=slab[physof(L)]; }
}

// ---------------- pass D: window qubits 2..7, diag outer only, expectation fused ----------------
__global__ __launch_bounds__(512,4) void passD_kernel(const cplx* __restrict__ S1,
                                                      const cplx* __restrict__ gin,
                                                      float* __restrict__ partial){
  __shared__ cplx slab[4096];
  __shared__ cplx sS[768];
  THREAD_SPLIT
  int s=blockIdx.x>>2, dd=blockIdx.x&3;
  int r67=dd, c67=dd;
  for (int i=t;i<768;i+=512) sS[i]=S1[i];
  const cplx* g = gin + (size_t)s*65536;
  #pragma unroll
  for (int j=0;j<8;j++){
    int f = (j<<9)|t, mI = f>>8, told = f&255;
    cplx v = g[mI*4096 + (((r67<<4)|(told>>4))<<6) + ((c67<<4)|(told&15))];
    int rlB = ((told>>4)<<2)|(mI>>2);
    int clB = ((told&15)<<2)|(mI&3);
    slab[physof((rlB<<6)|clB)] = v;
  }
  __syncthreads();
  STG(4,5,2) STG7(4,6,1)
  STG(5,4,3) STG(5,5,2) STG7(5,6,1)
  if (t < 64){
    float v = slab[physof(t*65)].x;
    #pragma unroll
    for (int o=32;o>0;o>>=1) v += __shfl_down(v,o,64);
    if (t==0) partial[s*4+dd] = (dd&2) ? -v : v;
  }
}

__global__ void final_kernel(const float* __restrict__ partial, float* __restrict__ out){
  int t = threadIdx.x;
  if (t < BATCH) out[t] = partial[4*t]+partial[4*t+1]+partial[4*t+2]+partial[4*t+3];
}

extern "C" void kernel_launch(void* const* d_in, const int* in_sizes, int n_in,
                              void* d_out, int out_size, void* d_ws, size_t ws_size,
                              hipStream_t stream) {
  const float* x = (const float*)d_in[0];   // [32,8]
  const float* w = (const float*)d_in[1];   // [6,8,2]
  float* out = (float*)d_out;               // [32,1] f32
  char* ws = (char*)d_ws;

  cplx*  buf0    = (cplx*)ws;                                   // 16 MB
  cplx*  buf1    = (cplx*)(ws + (size_t)16777216);              // 16 MB
  cplx*  S1      = (cplx*)(ws + (size_t)33554432);              // 6 KB
  float* m       = (float*)(ws + (size_t)33554432 + 6144);      // 4 KB
  float* partial = (float*)(ws + (size_t)33554432 + 6144 + 4096);

  prep_kernel<<<1, 256, 0, stream>>>(x, w, S1, m);
  passA_kernel<<<BATCH*16, 512, 0, stream>>>(S1, m, buf0);
  passB_kernel<<<BATCH*16, 512, 0, stream>>>(S1, buf0, buf1);
  passC_kernel<<<BATCH*16, 512, 0, stream>>>(S1, buf1, buf0);
  passD_kernel<<<BATCH*4, 512, 0, stream>>>(S1, buf0, partial);
  final_kernel<<<1, 64, 0, stream>>>(partial, out);
}

// Round 5
// 102.230 us; speedup vs baseline: 1.3248x; 1.3248x over previous
//
#include <hip/hip_runtime.h>
#include <cmath>

// Noisy 8-qubit density-matrix sim, batch 32, depth 6 — 4-pass, 6-qubit-window,
// 256-thread blocks, 16 els/thread (full stage-group per thread, no split).
// Stage cost cut: R superop factored as N1·Drz·(Y⊗Y) = two real 2x2 rotations
// + fused sparse complex N1·Drz (float4 of constants per (l,q): cy,sy,Px,Py).
// Per-stage XOR bases (u=1..5) hoisted to kernel entry. VGPR capped at 128 via
// __launch_bounds__(256,4) -> 4 blocks/CU (slab 32KB + 1KB consts).

typedef float2 cplx;

#define BATCH 32
#define DEPTH 6

__device__ __forceinline__ cplx cmul(cplx a, cplx b){
  return make_float2(a.x*b.x - a.y*b.y, a.x*b.y + a.y*b.x);
}
__device__ __forceinline__ cplx cscale(float s, cplx a){ return make_float2(s*a.x, s*a.y); }

struct N1C { float A,B,C,D,E; };
__device__ __forceinline__ N1C noise_coeffs(float g){
  float ga = g*0.3f, gp = g*0.2f, p = g*0.5f;
  N1C n;
  n.A = 1.0f - 2.0f*p/3.0f;
  n.D = 2.0f*p/3.0f;
  n.B = ga*n.A + n.D*(1.0f-ga);
  n.E = n.D*ga + n.A*(1.0f-ga);
  n.C = (1.0f - 4.0f*p/3.0f) * sqrtf(1.0f-ga) * sqrtf(1.0f-gp);
  return n;
}

// swizzle: phys = L ^ rot-left-3(row-local)
__device__ __forceinline__ int physof(int L){
  int rl = L >> 6;
  int rot = ((rl<<3)|(rl>>3)) & 63;
  return L ^ rot;
}
__device__ __forceinline__ constexpr int KPc(int p){
  return (p < 6) ? (1<<p) : ((1<<p) | (1 << (((p-6)+3)%6)));
}

// per-stage lane-bit -> free-logical-position tables (from round 3; conflict-checked)
template<int U>
__device__ __forceinline__ int base_for(int t){
  constexpr int P[6][8] = {
    {0,0,0,0,0,0,0,0},
    {9,10,2,3,4,5,8,11},   // u=1 (active {0,1,6,7})
    {0,10,11,3,4,5,6,9},   // u=2 (active {1,2,7,8})
    {0,1,11,6,4,5,7,10},   // u=3 (active {2,3,8,9})
    {0,1,2,6,5,7,8,11},    // u=4 (active {3,4,9,10})
    {0,1,2,3,7,8,6,9}};    // u=5 (active {4,5,10,11})
  int b = 0;
  #pragma unroll
  for (int i=0;i<8;i++) b ^= (-((t>>i)&1)) & KPc(P[U][i]);
  return b;
}

__device__ __forceinline__ void rot_pair(cplx& v0, cplx& v1, float cy, float sy){
  cplx a=v0, b=v1;
  v0 = make_float2(cy*a.x - sy*b.x, cy*a.y - sy*b.y);
  v1 = make_float2(sy*a.x + cy*b.x, sy*a.y + cy*b.y);
}

// ---------------- prep: per-(l,q) float4 {cy,sy,Px,Py} + encode 2x2s ----------------
__global__ __launch_bounds__(256) void prep_kernel(const float* __restrict__ x,
                                                   const float* __restrict__ w,
                                                   float4* __restrict__ S1,
                                                   float* __restrict__ m){
  int t = threadIdx.x;
  N1C n1 = noise_coeffs(0.0003f);
  if (t < DEPTH*8){
    float w0 = w[t*2 + 0];
    float w1 = w[t*2 + 1];
    S1[t] = make_float4(cosf(0.5f*w0), sinf(0.5f*w0),
                        n1.C*cosf(w1), -n1.C*sinf(w1));   // P = C1*e^{-i w1}
  }
  {
    int b = t >> 3, i = t & 7;
    float xv = x[b*8+i];
    float c = cosf(0.5f*xv), s = sinf(0.5f*xv);
    float p00=c*c, p01=c*s, p11=s*s;
    float* mm = m + t*4;
    mm[0] = n1.A*p00 + n1.B*p11;
    mm[1] = n1.C*p01;
    mm[2] = n1.C*p01;
    mm[3] = n1.D*p00 + n1.E*p11;
  }
}

// ---------------- fused stage: CNOT+noise2 pair + factored R(ctl) [+ R7(tgt)] ----------------
// h idx = a<<3 | b<<2 | cc<<1 | d   (a=row-ctl, b=row-tgt, cc=col-ctl, d=col-tgt)
template<int U, bool R7F>
__device__ __forceinline__ void do_stage(cplx* __restrict__ slab, float4 rc, float4 rc7,
                                         int bp, N1C n1, N1C n2){
  constexpr int KA=KPc(6+U), KB=KPc(5+U), KC=1<<U, KD=1<<(U-1);
  cplx h[16];
  // gather with CNOT permutation folded in
  #pragma unroll
  for (int idx=0; idx<16; idx++){
    int a=(idx>>3)&1, b=(idx>>2)&1, cc=(idx>>1)&1, d=idx&1;
    int pos = bp ^ (a?KA:0) ^ ((b^a)?KB:0) ^ (cc?KC:0) ^ ((d^cc)?KD:0);
    h[idx] = slab[pos];
  }
  // noise2 on ctl wire (a,cc) per (b,d)
  #pragma unroll
  for (int b=0;b<2;b++)
    #pragma unroll
    for (int d=0;d<2;d++){
      int i=(b<<2)|d;
      cplx t00=h[i], t11=h[i|10];
      h[i]    = make_float2(n2.A*t00.x+n2.B*t11.x, n2.A*t00.y+n2.B*t11.y);
      h[i|10] = make_float2(n2.D*t00.x+n2.E*t11.x, n2.D*t00.y+n2.E*t11.y);
      h[i|2]  = cscale(n2.C,h[i|2]);
      h[i|8]  = cscale(n2.C,h[i|8]);
    }
  // noise2 on tgt wire (b,d) per (a,cc)
  #pragma unroll
  for (int a=0;a<2;a++)
    #pragma unroll
    for (int cc=0;cc<2;cc++){
      int i=(a<<3)|(cc<<1);
      cplx t00=h[i], t11=h[i|5];
      h[i]   = make_float2(n2.A*t00.x+n2.B*t11.x, n2.A*t00.y+n2.B*t11.y);
      h[i|5] = make_float2(n2.D*t00.x+n2.E*t11.x, n2.D*t00.y+n2.E*t11.y);
      h[i|1] = cscale(n2.C,h[i|1]);
      h[i|4] = cscale(n2.C,h[i|4]);
    }
  // R(ctl) on (a,cc):  Ycol (cc pairs), Yrow (a pairs), then fused N1*Drz
  {
    float cy=rc.x, sy=rc.y;
    #pragma unroll
    for (int a=0;a<2;a++)
      #pragma unroll
      for (int b=0;b<2;b++)
        #pragma unroll
        for (int d=0;d<2;d++){
          int i=(a<<3)|(b<<2)|d;
          rot_pair(h[i], h[i|2], cy, sy);
        }
    #pragma unroll
    for (int b=0;b<2;b++)
      #pragma unroll
      for (int cc=0;cc<2;cc++)
        #pragma unroll
        for (int d=0;d<2;d++){
          int i=(b<<2)|(cc<<1)|d;
          rot_pair(h[i], h[i|8], cy, sy);
        }
    cplx p  = make_float2(rc.z, rc.w);
    cplx pc = make_float2(rc.z, -rc.w);
    #pragma unroll
    for (int b=0;b<2;b++)
      #pragma unroll
      for (int d=0;d<2;d++){
        int i=(b<<2)|d;
        cplx t00=h[i], t11=h[i|10];
        h[i]    = make_float2(n1.A*t00.x+n1.B*t11.x, n1.A*t00.y+n1.B*t11.y);
        h[i|10] = make_float2(n1.D*t00.x+n1.E*t11.x, n1.D*t00.y+n1.E*t11.y);
        h[i|2]  = cmul(p,  h[i|2]);
        h[i|8]  = cmul(pc, h[i|8]);
      }
  }
  // R7 on (b,d) (only for T(6,l))
  if (R7F){
    float cy=rc7.x, sy=rc7.y;
    #pragma unroll
    for (int a=0;a<2;a++)
      #pragma unroll
      for (int b=0;b<2;b++)
        #pragma unroll
        for (int cc=0;cc<2;cc++){
          int i=(a<<3)|(b<<2)|(cc<<1);
          rot_pair(h[i], h[i|1], cy, sy);
        }
    #pragma unroll
    for (int a=0;a<2;a++)
      #pragma unroll
      for (int cc=0;cc<2;cc++)
        #pragma unroll
        for (int d=0;d<2;d++){
          int i=(a<<3)|(cc<<1)|d;
          rot_pair(h[i], h[i|4], cy, sy);
        }
    cplx p  = make_float2(rc7.z, rc7.w);
    cplx pc = make_float2(rc7.z, -rc7.w);
    #pragma unroll
    for (int a=0;a<2;a++)
      #pragma unroll
      for (int cc=0;cc<2;cc++){
        int i=(a<<3)|(cc<<1);
        cplx t00=h[i], t11=h[i|5];
        h[i]   = make_float2(n1.A*t00.x+n1.B*t11.x, n1.A*t00.y+n1.B*t11.y);
        h[i|5] = make_float2(n1.D*t00.x+n1.E*t11.x, n1.D*t00.y+n1.E*t11.y);
        h[i|1] = cmul(p,  h[i|1]);
        h[i|4] = cmul(pc, h[i|4]);
      }
  }
  // scatter (unpermuted)
  #pragma unroll
  for (int idx=0; idx<16; idx++){
    int a=(idx>>3)&1, b=(idx>>2)&1, cc=(idx>>1)&1, d=idx&1;
    int pos = bp ^ (a?KA:0) ^ (b?KB:0) ^ (cc?KC:0) ^ (d?KD:0);
    slab[pos] = h[idx];
  }
}

#define STG(l,q,u)  { float4 rc = sS[(l)*8+(q)]; \
                      do_stage<u,false>(slab, rc, rc, b##u, n1, n2); } __syncthreads();
#define STG7(l,q,u) { float4 rc = sS[(l)*8+(q)]; float4 rc7 = sS[(l)*8+7]; \
                      do_stage<u,true>(slab, rc, rc7, b##u, n1, n2); } __syncthreads();

#define COMMON_SETUP \
  int t = threadIdx.x; \
  N1C n1 = noise_coeffs(0.0003f); \
  N1C n2 = noise_coeffs(0.0065f); \
  int b1=base_for<1>(t), b2=base_for<2>(t), b3=base_for<3>(t), \
      b4=base_for<4>(t), b5=base_for<5>(t); \
  (void)b1;(void)b2;(void)b3;(void)b4;(void)b5;

// ---------------- pass A: window qubits 0..5, outer = qubit 6,7 bits ----------------
__global__ __launch_bounds__(256,4) void passA_kernel(const float4* __restrict__ S1,
                                                      const float* __restrict__ m,
                                                      cplx* __restrict__ gout){
  __shared__ cplx slab[4096];
  __shared__ float4 sS[48];
  __shared__ float sm[32];
  COMMON_SETUP
  int s = blockIdx.x >> 4, oA = blockIdx.x & 15;
  if (t<48) sS[t]=S1[t];
  if (t<32) sm[t]=m[s*32+t];
  __syncthreads();
  int oAr=oA>>2, oAc=oA&3;
  float m67 = sm[24+(oAr>>1)*2+(oAc>>1)] * sm[28+(oAr&1)*2+(oAc&1)];
  #pragma unroll
  for (int k=0;k<16;k++){
    int L=(k<<8)|t, rl=L>>6, cl=L&63;
    float v=m67;
    #pragma unroll
    for (int i=0;i<6;i++) v *= sm[i*4+((rl>>(5-i))&1)*2+((cl>>(5-i))&1)];
    slab[physof(L)]=make_float2(v,0.f);
  }
  __syncthreads();
  STG(0,0,5) STG(0,1,4) STG(0,2,3) STG(0,3,2) STG(0,4,1)
  STG(1,0,5) STG(1,1,4) STG(1,2,3) STG(1,3,2)
  STG(2,0,5) STG(2,1,4) STG(2,2,3)
  STG(3,0,5) STG(3,1,4)
  STG(4,0,5)
  cplx* g = gout + (size_t)s*65536 + oA*4096;
  #pragma unroll
  for (int k=0;k<16;k++){ int L=(k<<8)|t; g[L]=slab[physof(L)]; }
}

// ---------------- pass B: window qubits 2..7, outer = qubit 0,1 bits ----------------
__global__ __launch_bounds__(256,4) void passB_kernel(const float4* __restrict__ S1,
                                                      const cplx* __restrict__ gin,
                                                      cplx* __restrict__ gout){
  __shared__ cplx slab[4096];
  __shared__ float4 sS[48];
  COMMON_SETUP
  int s=blockIdx.x>>4, oB=blockIdx.x&15;
  int r67=oB>>2, c67=oB&3;
  if (t<48) sS[t]=S1[t];
  const cplx* g = gin + (size_t)s*65536;
  #pragma unroll
  for (int mI=0;mI<16;mI++){
    cplx v = g[mI*4096 + (((r67<<4)|(t>>4))<<6) + ((c67<<4)|(t&15))];
    int rlB = ((t>>4)<<2)|(mI>>2);
    int clB = ((t&15)<<2)|(mI&3);
    slab[physof((rlB<<6)|clB)] = v;
  }
  __syncthreads();
  STG(0,5,2) STG7(0,6,1)
  STG(1,4,3) STG(1,5,2) STG7(1,6,1)
  STG(2,3,4) STG(2,4,3) STG(2,5,2) STG7(2,6,1)
  STG(3,2,5) STG(3,3,4) STG(3,4,3) STG(3,5,2) STG7(3,6,1)
  cplx* go = gout + (size_t)s*65536 + oB*4096;
  #pragma unroll
  for (int k=0;k<16;k++){ int L=(k<<8)|t; go[L]=slab[physof(L)]; }
}

// ---------------- pass C: window qubits 0..5, reads pass-B layout ----------------
__global__ __launch_bounds__(256,4) void passC_kernel(const float4* __restrict__ S1,
                                                      const cplx* __restrict__ gin,
                                                      cplx* __restrict__ gout){
  __shared__ cplx slab[4096];
  __shared__ float4 sS[48];
  COMMON_SETUP
  int s=blockIdx.x>>4, oC=blockIdx.x&15;
  int oCr=oC>>2, oCc=oC&3;
  if (t<48) sS[t]=S1[t];
  const cplx* g = gin + (size_t)s*65536;
  #pragma unroll
  for (int mI=0;mI<16;mI++){
    int xx=t>>4, y=t&15;
    cplx v = g[mI*4096 + (((xx<<2)|oCr)<<6) + ((y<<2)|oCc)];
    int rlC = ((mI>>2)<<4)|xx;
    int clC = ((mI&3)<<4)|y;
    slab[physof((rlC<<6)|clC)] = v;
  }
  __syncthreads();
  STG(4,1,4) STG(4,2,3) STG(4,3,2) STG(4,4,1)
  STG(5,0,5) STG(5,1,4) STG(5,2,3) STG(5,3,2)
  cplx* go = gout + (size_t)s*65536 + oC*4096;
  #pragma unroll
  for (int k=0;k<16;k++){ int L=(k<<8)|t; go[L]=slab[physof(L)]; }
}

// ---------------- pass D: window qubits 2..7, diag outer only, expectation fused ----------------
__global__ __launch_bounds__(256,4) void passD_kernel(const float4* __restrict__ S1,
                                                      const cplx* __restrict__ gin,
                                                      float* __restrict__ partial){
  __shared__ cplx slab[4096];
  __shared__ float4 sS[48];
  COMMON_SETUP
  int s=blockIdx.x>>2, dd=blockIdx.x&3;
  int r67=dd, c67=dd;
  if (t<48) sS[t]=S1[t];
  const cplx* g = gin + (size_t)s*65536;
  #pragma unroll
  for (int mI=0;mI<16;mI++){
    cplx v = g[mI*4096 + (((r67<<4)|(t>>4))<<6) + ((c67<<4)|(t&15))];
    int rlB = ((t>>4)<<2)|(mI>>2);
    int clB = ((t&15)<<2)|(mI&3);
    slab[physof((rlB<<6)|clB)] = v;
  }
  __syncthreads();
  STG(4,5,2) STG7(4,6,1)
  STG(5,4,3) STG(5,5,2) STG7(5,6,1)
  if (t < 64){
    float v = slab[physof(t*65)].x;
    #pragma unroll
    for (int o=32;o>0;o>>=1) v += __shfl_down(v,o,64);
    if (t==0) partial[s*4+dd] = (dd&2) ? -v : v;
  }
}

__global__ void final_kernel(const float* __restrict__ partial, float* __restrict__ out){
  int t = threadIdx.x;
  if (t < BATCH) out[t] = partial[4*t]+partial[4*t+1]+partial[4*t+2]+partial[4*t+3];
}

extern "C" void kernel_launch(void* const* d_in, const int* in_sizes, int n_in,
                              void* d_out, int out_size, void* d_ws, size_t ws_size,
                              hipStream_t stream) {
  const float* x = (const float*)d_in[0];   // [32,8]
  const float* w = (const float*)d_in[1];   // [6,8,2]
  float* out = (float*)d_out;               // [32,1] f32
  char* ws = (char*)d_ws;

  cplx*   buf0    = (cplx*)ws;                                   // 16 MB
  cplx*   buf1    = (cplx*)(ws + (size_t)16777216);              // 16 MB
  float4* S1      = (float4*)(ws + (size_t)33554432);            // 768 B
  float*  m       = (float*)(ws + (size_t)33554432 + 1024);      // 4 KB
  float*  partial = (float*)(ws + (size_t)33554432 + 1024 + 4096);

  prep_kernel<<<1, 256, 0, stream>>>(x, w, S1, m);
  passA_kernel<<<BATCH*16, 256, 0, stream>>>(S1, m, buf0);
  passB_kernel<<<BATCH*16, 256, 0, stream>>>(S1, buf0, buf1);
  passC_kernel<<<BATCH*16, 256, 0, stream>>>(S1, buf1, buf0);
  passD_kernel<<<BATCH*4, 256, 0, stream>>>(S1, buf0, partial);
  final_kernel<<<1, 64, 0, stream>>>(partial, out);
}

// Round 6
// 76.096 us; speedup vs baseline: 1.7798x; 1.3434x over previous
//
#include <hip/hip_runtime.h>
#include <cmath>

// Noisy 8-qubit density-matrix sim, batch 32, depth 6 — ADJOINT (Heisenberg) version.
// E_b = Tr(Z0 · Λ(rho_b)) = Tr(Λ†(Z0) · rho_b);  rho_b = ⊗_q m_{b,q} (real 2x2s).
// Backward-evolve O = Λ†(Z0) ONCE (65536 cplx), then contract with 32 product states.
// Adjoint of fused stage T = R7∘R∘N2t∘N2c∘CNOT is T† = CNOT∘N2c†∘N2t†∘R†∘R7†:
//   noise superop adjoint = swap B<->D; RZ phase conjugates; RY angle negates;
//   CNOT self-adjoint -> XOR fold moves from gather to scatter.
// Backward schedule = exact reverse of the verified forward schedule:
//   D†(5 stages, W1, Z0-init analytic) -> C†(8, W2) -> B†(14, W1) -> A†(15, W2).
// Same 6-qubit windows, phys swizzle, bank tables, and retile formulas as forward.

typedef float2 cplx;

#define BATCH 32
#define DEPTH 6

__device__ __forceinline__ cplx cmul(cplx a, cplx b){
  return make_float2(a.x*b.x - a.y*b.y, a.x*b.y + a.y*b.x);
}

struct N1C { float A,B,C,D,E; };
__device__ __forceinline__ N1C noise_coeffs(float g){
  float ga = g*0.3f, gp = g*0.2f, p = g*0.5f;
  N1C n;
  n.A = 1.0f - 2.0f*p/3.0f;
  n.D = 2.0f*p/3.0f;
  n.B = ga*n.A + n.D*(1.0f-ga);
  n.E = n.D*ga + n.A*(1.0f-ga);
  n.C = (1.0f - 4.0f*p/3.0f) * sqrtf(1.0f-ga) * sqrtf(1.0f-gp);
  return n;
}
// adjoint channel: transpose of the real sparse superop = swap B<->D
__device__ __forceinline__ N1C mkadj(N1C n){
  N1C a; a.A=n.A; a.B=n.D; a.C=n.C; a.D=n.B; a.E=n.E; return a;
}

// swizzle: phys = L ^ rot-left-3(row-local)   (GF(2)-linear)
__device__ __forceinline__ int physof(int L){
  int rl = L >> 6;
  int rot = ((rl<<3)|(rl>>3)) & 63;
  return L ^ rot;
}
__device__ __forceinline__ constexpr int KPc(int p){
  return (p < 6) ? (1<<p) : ((1<<p) | (1 << (((p-6)+3)%6)));
}

// per-stage lane-bit -> free-logical-position tables (round-3, conflict-checked)
template<int U>
__device__ __forceinline__ int base_for(int t){
  constexpr int P[6][8] = {
    {0,0,0,0,0,0,0,0},
    {9,10,2,3,4,5,8,11},   // u=1
    {0,10,11,3,4,5,6,9},   // u=2
    {0,1,11,6,4,5,7,10},   // u=3
    {0,1,2,6,5,7,8,11},    // u=4
    {0,1,2,3,7,8,6,9}};    // u=5
  int b = 0;
  #pragma unroll
  for (int i=0;i<8;i++) b ^= (-((t>>i)&1)) & KPc(P[U][i]);
  return b;
}

__device__ __forceinline__ void rot_pair(cplx& v0, cplx& v1, float cy, float sy){
  cplx a=v0, b=v1;
  v0 = make_float2(cy*a.x - sy*b.x, cy*a.y - sy*b.y);
  v1 = make_float2(sy*a.x + cy*b.x, sy*a.y + cy*b.y);
}

// ---------------- prep: per-(l,q) float4 {cy,sy,Px,Py} + encode 2x2s ----------------
__global__ __launch_bounds__(256) void prep_kernel(const float* __restrict__ x,
                                                   const float* __restrict__ w,
                                                   float4* __restrict__ S1,
                                                   float* __restrict__ m){
  int t = threadIdx.x;
  N1C n1 = noise_coeffs(0.0003f);
  if (t < DEPTH*8){
    float w0 = w[t*2 + 0];
    float w1 = w[t*2 + 1];
    S1[t] = make_float4(cosf(0.5f*w0), sinf(0.5f*w0),
                        n1.C*cosf(w1), -n1.C*sinf(w1));   // P = C1*e^{-i w1}
  }
  {
    int b = t >> 3, i = t & 7;
    float xv = x[b*8+i];
    float c = cosf(0.5f*xv), s = sinf(0.5f*xv);
    float p00=c*c, p01=c*s, p11=s*s;
    float* mm = m + t*4;
    mm[0] = n1.A*p00 + n1.B*p11;
    mm[1] = n1.C*p01;
    mm[2] = n1.C*p01;
    mm[3] = n1.D*p00 + n1.E*p11;
  }
}

// ---------------- adjoint fused stage ----------------
// h idx = a<<3 | b<<2 | cc<<1 | d  (a=row-ctl, b=row-tgt, cc=col-ctl, d=col-tgt)
// sequence: straight gather -> [R7†] -> Rctl† -> N2t† -> N2c† -> scatter w/ CNOT fold
template<int U, bool R7F>
__device__ __forceinline__ void do_stage_adj(cplx* __restrict__ slab, float4 rc, float4 rc7,
                                             int bp, N1C n1, N1C n2){
  constexpr int KA=KPc(6+U), KB=KPc(5+U), KC=1<<U, KD=1<<(U-1);
  cplx h[16];
  // straight gather
  #pragma unroll
  for (int idx=0; idx<16; idx++){
    int a=(idx>>3)&1, b=(idx>>2)&1, cc=(idx>>1)&1, d=idx&1;
    int pos = bp ^ (a?KA:0) ^ (b?KB:0) ^ (cc?KC:0) ^ (d?KD:0);
    h[idx] = slab[pos];
  }
  // R7† on (b,d): sparse-adjoint first, then Y(-θ) rotations
  if (R7F){
    cplx p  = make_float2(rc7.z, -rc7.w);   // conj(P) on 01
    cplx pc = make_float2(rc7.z,  rc7.w);   // P on 10
    #pragma unroll
    for (int a=0;a<2;a++)
      #pragma unroll
      for (int cc=0;cc<2;cc++){
        int i=(a<<3)|(cc<<1);
        cplx t00=h[i], t11=h[i|5];
        h[i]   = make_float2(n1.A*t00.x+n1.B*t11.x, n1.A*t00.y+n1.B*t11.y);
        h[i|5] = make_float2(n1.D*t00.x+n1.E*t11.x, n1.D*t00.y+n1.E*t11.y);
        h[i|1] = cmul(p,  h[i|1]);
        h[i|4] = cmul(pc, h[i|4]);
      }
    float cy=rc7.x, sy=-rc7.y;
    #pragma unroll
    for (int a=0;a<2;a++)
      #pragma unroll
      for (int b=0;b<2;b++)
        #pragma unroll
        for (int cc=0;cc<2;cc++){
          int i=(a<<3)|(b<<2)|(cc<<1);
          rot_pair(h[i], h[i|1], cy, sy);
        }
    #pragma unroll
    for (int a=0;a<2;a++)
      #pragma unroll
      for (int cc=0;cc<2;cc++)
        #pragma unroll
        for (int d=0;d<2;d++){
          int i=(a<<3)|(cc<<1)|d;
          rot_pair(h[i], h[i|4], cy, sy);
        }
  }
  // Rctl† on (a,cc): sparse-adjoint first, then Y(-θ) rotations
  {
    cplx p  = make_float2(rc.z, -rc.w);
    cplx pc = make_float2(rc.z,  rc.w);
    #pragma unroll
    for (int b=0;b<2;b++)
      #pragma unroll
      for (int d=0;d<2;d++){
        int i=(b<<2)|d;
        cplx t00=h[i], t11=h[i|10];
        h[i]    = make_float2(n1.A*t00.x+n1.B*t11.x, n1.A*t00.y+n1.B*t11.y);
        h[i|10] = make_float2(n1.D*t00.x+n1.E*t11.x, n1.D*t00.y+n1.E*t11.y);
        h[i|2]  = cmul(p,  h[i|2]);
        h[i|8]  = cmul(pc, h[i|8]);
      }
    float cy=rc.x, sy=-rc.y;
    #pragma unroll
    for (int a=0;a<2;a++)
      #pragma unroll
      for (int b=0;b<2;b++)
        #pragma unroll
        for (int d=0;d<2;d++){
          int i=(a<<3)|(b<<2)|d;
          rot_pair(h[i], h[i|2], cy, sy);
        }
    #pragma unroll
    for (int b=0;b<2;b++)
      #pragma unroll
      for (int cc=0;cc<2;cc++)
        #pragma unroll
        for (int d=0;d<2;d++){
          int i=(b<<2)|(cc<<1)|d;
          rot_pair(h[i], h[i|8], cy, sy);
        }
  }
  // N2† on tgt wire (b,d)
  #pragma unroll
  for (int a=0;a<2;a++)
    #pragma unroll
    for (int cc=0;cc<2;cc++){
      int i=(a<<3)|(cc<<1);
      cplx t00=h[i], t11=h[i|5];
      h[i]   = make_float2(n2.A*t00.x+n2.B*t11.x, n2.A*t00.y+n2.B*t11.y);
      h[i|5] = make_float2(n2.D*t00.x+n2.E*t11.x, n2.D*t00.y+n2.E*t11.y);
      h[i|1] = make_float2(n2.C*h[i|1].x, n2.C*h[i|1].y);
      h[i|4] = make_float2(n2.C*h[i|4].x, n2.C*h[i|4].y);
    }
  // N2† on ctl wire (a,cc)
  #pragma unroll
  for (int b=0;b<2;b++)
    #pragma unroll
    for (int d=0;d<2;d++){
      int i=(b<<2)|d;
      cplx t00=h[i], t11=h[i|10];
      h[i]    = make_float2(n2.A*t00.x+n2.B*t11.x, n2.A*t00.y+n2.B*t11.y);
      h[i|10] = make_float2(n2.D*t00.x+n2.E*t11.x, n2.D*t00.y+n2.E*t11.y);
      h[i|2]  = make_float2(n2.C*h[i|2].x, n2.C*h[i|2].y);
      h[i|8]  = make_float2(n2.C*h[i|8].x, n2.C*h[i|8].y);
    }
  // scatter with CNOT fold (CNOT applied LAST in adjoint)
  #pragma unroll
  for (int idx=0; idx<16; idx++){
    int a=(idx>>3)&1, b=(idx>>2)&1, cc=(idx>>1)&1, d=idx&1;
    int pos = bp ^ (a?KA:0) ^ ((b^a)?KB:0) ^ (cc?KC:0) ^ ((d^cc)?KD:0);
    slab[pos] = h[idx];
  }
}

#define ASTG(l,q,u)  { float4 rc = sS[(l)*8+(q)]; \
                       do_stage_adj<u,false>(slab, rc, rc, b##u, n1a, n2a); } __syncthreads();
#define ASTG7(l,q,u) { float4 rc = sS[(l)*8+(q)]; float4 rc7 = sS[(l)*8+7]; \
                       do_stage_adj<u,true>(slab, rc, rc7, b##u, n1a, n2a); } __syncthreads();

#define BSETUP \
  int t = threadIdx.x; \
  N1C n1a = mkadj(noise_coeffs(0.0003f)); \
  N1C n2a = mkadj(noise_coeffs(0.0065f)); \
  int b1=base_for<1>(t), b2=base_for<2>(t), b3=base_for<3>(t), \
      b4=base_for<4>(t), b5=base_for<5>(t); \
  (void)b1;(void)b2;(void)b3;(void)b4;(void)b5;

// ---------------- bD: W1 window (qubits 2..7), Z0 init analytic, 5 stages ----------------
// W1 buffer layout: f = ((r>>6)<<2 | (c>>6))*4096 + (r&63)*64 + (c&63)
__global__ __launch_bounds__(256) void bD_kernel(const float4* __restrict__ S1,
                                                 cplx* __restrict__ gout){
  __shared__ cplx slab[4096];
  __shared__ float4 sS[48];
  BSETUP
  int oB = blockIdx.x;             // (r67<<2)|c67
  int r67 = oB>>2, c67 = oB&3;
  if (t<48) sS[t]=S1[t];
  cplx* go = gout + oB*4096;
  if (r67 != c67){
    // Z0 block is identically zero and stages keep it zero
    #pragma unroll
    for (int k=0;k<16;k++) go[(k<<8)|t] = make_float2(0.f,0.f);
    return;
  }
  float sgn = (r67 & 2) ? -1.f : 1.f;    // qubit0 = r bit7 = r67 bit1
  #pragma unroll
  for (int k=0;k<16;k++){
    int L=(k<<8)|t, rl=L>>6, cl=L&63;
    slab[physof(L)] = make_float2((rl==cl)?sgn:0.f, 0.f);
  }
  __syncthreads();
  ASTG7(5,6,1) ASTG(5,5,2) ASTG(5,4,3) ASTG7(4,6,1) ASTG(4,5,2)
  #pragma unroll
  for (int k=0;k<16;k++){ int L=(k<<8)|t; go[L]=slab[physof(L)]; }
}

// ---------------- bC: W2 window (qubits 0..5), reads W1 layout, 8 stages ----------------
// W2 buffer layout: f = ((r&3)<<2 | (c&3))*4096 + (r>>2)*64 + (c>>2)
__global__ __launch_bounds__(256) void bC_kernel(const float4* __restrict__ S1,
                                                 const cplx* __restrict__ gin,
                                                 cplx* __restrict__ gout){
  __shared__ cplx slab[4096];
  __shared__ float4 sS[48];
  BSETUP
  int oC = blockIdx.x;
  int oCr = oC>>2, oCc = oC&3;
  if (t<48) sS[t]=S1[t];
  #pragma unroll
  for (int mI=0;mI<16;mI++){
    int xx=t>>4, y=t&15;
    cplx v = gin[mI*4096 + (((xx<<2)|oCr)<<6) + ((y<<2)|oCc)];
    int rlC = ((mI>>2)<<4)|xx;
    int clC = ((mI&3)<<4)|y;
    slab[physof((rlC<<6)|clC)] = v;
  }
  __syncthreads();
  ASTG(5,3,2) ASTG(5,2,3) ASTG(5,1,4) ASTG(5,0,5)
  ASTG(4,4,1) ASTG(4,3,2) ASTG(4,2,3) ASTG(4,1,4)
  cplx* go = gout + oC*4096;
  #pragma unroll
  for (int k=0;k<16;k++){ int L=(k<<8)|t; go[L]=slab[physof(L)]; }
}

// ---------------- bB: W1 window, reads W2 layout, 14 stages ----------------
__global__ __launch_bounds__(256) void bB_kernel(const float4* __restrict__ S1,
                                                 const cplx* __restrict__ gin,
                                                 cplx* __restrict__ gout){
  __shared__ cplx slab[4096];
  __shared__ float4 sS[48];
  BSETUP
  int oB = blockIdx.x;
  int r67 = oB>>2, c67 = oB&3;
  if (t<48) sS[t]=S1[t];
  #pragma unroll
  for (int mI=0;mI<16;mI++){
    cplx v = gin[mI*4096 + (((r67<<4)|(t>>4))<<6) + ((c67<<4)|(t&15))];
    int rlB = ((t>>4)<<2)|(mI>>2);
    int clB = ((t&15)<<2)|(mI&3);
    slab[physof((rlB<<6)|clB)] = v;
  }
  __syncthreads();
  ASTG7(3,6,1) ASTG(3,5,2) ASTG(3,4,3) ASTG(3,3,4) ASTG(3,2,5)
  ASTG7(2,6,1) ASTG(2,5,2) ASTG(2,4,3) ASTG(2,3,4)
  ASTG7(1,6,1) ASTG(1,5,2) ASTG(1,4,3)
  ASTG7(0,6,1) ASTG(0,5,2)
  cplx* go = gout + oB*4096;
  #pragma unroll
  for (int k=0;k<16;k++){ int L=(k<<8)|t; go[L]=slab[physof(L)]; }
}

// ---------------- bA: W2 window, reads W1 layout, 15 stages ----------------
__global__ __launch_bounds__(256) void bA_kernel(const float4* __restrict__ S1,
                                                 const cplx* __restrict__ gin,
                                                 cplx* __restrict__ gout){
  __shared__ cplx slab[4096];
  __shared__ float4 sS[48];
  BSETUP
  int oC = blockIdx.x;
  int oCr = oC>>2, oCc = oC&3;
  if (t<48) sS[t]=S1[t];
  #pragma unroll
  for (int mI=0;mI<16;mI++){
    int xx=t>>4, y=t&15;
    cplx v = gin[mI*4096 + (((xx<<2)|oCr)<<6) + ((y<<2)|oCc)];
    int rlC = ((mI>>2)<<4)|xx;
    int clC = ((mI&3)<<4)|y;
    slab[physof((rlC<<6)|clC)] = v;
  }
  __syncthreads();
  ASTG(4,0,5)
  ASTG(3,1,4) ASTG(3,0,5)
  ASTG(2,2,3) ASTG(2,1,4) ASTG(2,0,5)
  ASTG(1,3,2) ASTG(1,2,3) ASTG(1,1,4) ASTG(1,0,5)
  ASTG(0,4,1) ASTG(0,3,2) ASTG(0,2,3) ASTG(0,1,4) ASTG(0,0,5)
  cplx* go = gout + oC*4096;
  #pragma unroll
  for (int k=0;k<16;k++){ int L=(k<<8)|t; go[L]=slab[physof(L)]; }
}

// ---------------- expect: E_b = sum_f O[f].x * prod_q m[b,q][r_q,c_q] ----------------
// O in W2 layout: f = o*4096 + rl*64 + cl, r=(rl<<2)|(o>>2), c=(cl<<2)|(o&3)
__global__ __launch_bounds__(256) void expect_kernel(const cplx* __restrict__ O,
                                                     const float* __restrict__ m,
                                                     float* __restrict__ out){
  __shared__ float sm[32];
  __shared__ float red[4];
  int t = threadIdx.x, s = blockIdx.x;
  if (t<32) sm[t]=m[s*32+t];
  __syncthreads();
  int cl = t & 63;
  float p0[2],p1[2],p2[2],p3[2];
  float wbase;
  {
    // qubits 0..5 col bits come from cl (c bit 7-q = cl bit 5-q)
    float q4a = sm[16 + 0 + ((cl>>1)&1)], q4b = sm[16 + 2 + ((cl>>1)&1)];
    float q5a = sm[20 + 0 + (cl&1)],      q5b = sm[20 + 2 + (cl&1)];
    int r32 = t>>6;            // rl bits 1..0 = qubits 4,5 row bits
    float w4 = (r32>>1) ? q4b : q4a;
    float w5 = (r32&1)  ? q5b : q5a;
    wbase = w4 * w5;
    int c0=(cl>>5)&1, c1=(cl>>4)&1, c2=(cl>>3)&1, c3=(cl>>2)&1;
    p0[0]=sm[0+c0];  p0[1]=sm[2+c0];
    p1[0]=sm[4+c1];  p1[1]=sm[6+c1];
    p2[0]=sm[8+c2];  p2[1]=sm[10+c2];
    p3[0]=sm[12+c3]; p3[1]=sm[14+c3];
  }
  float acc = 0.f;
  for (int o=0;o<16;o++){
    int r6=(o>>3)&1, r7=(o>>2)&1, c6=(o>>1)&1, c7=o&1;
    float w67 = sm[24 + r6*2 + c6] * sm[28 + r7*2 + c7] * wbase;
    const cplx* Op = O + (o<<12) + t;
    #pragma unroll
    for (int rh=0; rh<16; rh++){
      float w = w67 * p0[(rh>>3)&1] * p1[(rh>>2)&1] * p2[(rh>>1)&1] * p3[rh&1];
      acc += Op[rh<<8].x * w;
    }
  }
  #pragma unroll
  for (int off=32;off>0;off>>=1) acc += __shfl_down(acc, off, 64);
  if ((t&63)==0) red[t>>6]=acc;
  __syncthreads();
  if (t==0) out[s] = red[0]+red[1]+red[2]+red[3];
}

extern "C" void kernel_launch(void* const* d_in, const int* in_sizes, int n_in,
                              void* d_out, int out_size, void* d_ws, size_t ws_size,
                              hipStream_t stream) {
  const float* x = (const float*)d_in[0];   // [32,8]
  const float* w = (const float*)d_in[1];   // [6,8,2]
  float* out = (float*)d_out;               // [32,1] f32
  char* ws = (char*)d_ws;

  cplx*   buf0 = (cplx*)ws;                           // 512 KB
  cplx*   buf1 = (cplx*)(ws + (size_t)1048576);       // 512 KB
  float4* S1   = (float4*)(ws + (size_t)2097152);     // 768 B
  float*  m    = (float*)(ws + (size_t)2097152 + 1024);

  prep_kernel<<<1, 256, 0, stream>>>(x, w, S1, m);
  bD_kernel<<<16, 256, 0, stream>>>(S1, buf0);
  bC_kernel<<<16, 256, 0, stream>>>(S1, buf0, buf1);
  bB_kernel<<<16, 256, 0, stream>>>(S1, buf1, buf0);
  bA_kernel<<<16, 256, 0, stream>>>(S1, buf0, buf1);
  expect_kernel<<<BATCH, 256, 0, stream>>>(buf1, m, out);
}

// Round 7
// 66.088 us; speedup vs baseline: 2.0493x; 1.1514x over previous
//
#include <hip/hip_runtime.h>
#include <cmath>

// Noisy 8-qubit density-matrix sim, batch 32, depth 6 — ADJOINT version, pair-split.
// E_b = Tr(Λ†(Z0) · rho_b); rho_b = ⊗_q m_{b,q}. Backward-evolve O = Λ†(Z0) once
// (65536 cplx), contract with 32 product states.
// This round: 512-thread blocks, each 16-el stage group split across a thread PAIR
// (adjacent lanes, wave-lockstep) on the row-target bit b. Adjoint stage order:
//   gather(straight) -> [R7†(full-16 dup)] -> Rctl† -> N2t†(cross via partner col X,
//   X re-runs Rctl†) -> N2c† -> scatter(CNOT fold).
// Z0 sparsity: bD runs only 4 diagonal outer tiles; bC zero-substitutes the rest.
// prep folded into all kernels; expect fused m-computation + atomicAdd (128 blocks).

typedef float2 cplx;

#define BATCH 32
#define DEPTH 6

__device__ __forceinline__ cplx cmul(cplx a, cplx b){
  return make_float2(a.x*b.x - a.y*b.y, a.x*b.y + a.y*b.x);
}
__device__ __forceinline__ cplx lc(float a, cplx u, float b, cplx v){
  return make_float2(a*u.x + b*v.x, a*u.y + b*v.y);
}
__device__ __forceinline__ cplx sc(float a, cplx u){ return make_float2(a*u.x, a*u.y); }

struct N1C { float A,B,C,D,E; };
__device__ __forceinline__ N1C noise_coeffs(float g){
  float ga = g*0.3f, gp = g*0.2f, p = g*0.5f;
  N1C n;
  n.A = 1.0f - 2.0f*p/3.0f;
  n.D = 2.0f*p/3.0f;
  n.B = ga*n.A + n.D*(1.0f-ga);
  n.E = n.D*ga + n.A*(1.0f-ga);
  n.C = (1.0f - 4.0f*p/3.0f) * sqrtf(1.0f-ga) * sqrtf(1.0f-gp);
  return n;
}
// adjoint channel = transpose = swap B<->D
__device__ __forceinline__ N1C mkadj(N1C n){
  N1C a; a.A=n.A; a.B=n.D; a.C=n.C; a.D=n.B; a.E=n.E; return a;
}

// swizzle: phys = L ^ rot-left-3(row-local)
__device__ __forceinline__ int physof(int L){
  int rl = L >> 6;
  int rot = ((rl<<3)|(rl>>3)) & 63;
  return L ^ rot;
}
__device__ __forceinline__ constexpr int KPc(int p){
  return (p < 6) ? (1<<p) : ((1<<p) | (1 << (((p-6)+3)%6)));
}

// round-4 split tables: lane=(gg&...)<<1|bsel, bsel drives logical pos 5+U (KB)
template<int U>
__device__ __forceinline__ int base_for(int g){
  constexpr int P[6][8] = {
    {0,0,0,0,0,0,0,0},
    {9,10,2,4,5, 3,8,11},   // u=1
    {0,10,11,3,5, 4,6,9},   // u=2
    {0,1,11,6,4, 5,7,10},   // u=3
    {1,2,6,7,5, 0,8,11},    // u=4
    {0,2,3,7,8, 1,6,9}};    // u=5
  int b = 0;
  #pragma unroll
  for (int i=0;i<8;i++) b ^= (-((g>>i)&1)) & KPc(P[U][i]);
  return b;
}

__device__ __forceinline__ void rot_pair(cplx& v0, cplx& v1, float cy, float sy){
  cplx a=v0, b=v1;
  v0 = make_float2(cy*a.x - sy*b.x, cy*a.y - sy*b.y);
  v1 = make_float2(sy*a.x + cy*b.x, sy*a.y + cy*b.y);
}

// ---------------- adjoint half-stage: thread owns b=bsel half ----------------
// own idx i = a*4 + cc*2 + d ; partner column X[j], j=(a<<1)|cc, (b,d)=(1-bsel,1-bsel)
template<int U>
__device__ __forceinline__ void astage_half(cplx* __restrict__ slab, float4 rc,
                                            int bp, int bsel, N1C n1a, N1C n2a,
                                            float al, float be, float ga, float de){
  constexpr int KA=KPc(6+U), KB=KPc(5+U), KC=1<<U, KD=1<<(U-1);
  int bb = bsel ? KB : 0;
  int xn = bsel ? 0 : (KB^KD);
  cplx h[8], X[4];
  #pragma unroll
  for (int i=0;i<8;i++){
    int a=(i>>2)&1, cc=(i>>1)&1, d=i&1;
    h[i] = slab[bp ^ bb ^ (a?KA:0) ^ (cc?KC:0) ^ (d?KD:0)];
  }
  #pragma unroll
  for (int j=0;j<4;j++){
    int a=j>>1, cc=j&1;
    X[j] = slab[bp ^ xn ^ (a?KA:0) ^ (cc?KC:0)];
  }
  cplx p  = make_float2(rc.z, -rc.w);
  cplx pc = make_float2(rc.z,  rc.w);
  float cy=rc.x, sy=-rc.y;
  // Rctl† on own: sparse (N1†·Drz†) then Y(-θ) rotations
  #pragma unroll
  for (int d=0;d<2;d++){
    cplx t00=h[d], t11=h[6+d];
    h[d]   = lc(n1a.A,t00, n1a.B,t11);
    h[6+d] = lc(n1a.D,t00, n1a.E,t11);
    h[2+d] = cmul(p,  h[2+d]);
    h[4+d] = cmul(pc, h[4+d]);
  }
  #pragma unroll
  for (int a=0;a<2;a++)
    #pragma unroll
    for (int d=0;d<2;d++) rot_pair(h[a*4+d], h[a*4+2+d], cy, sy);
  #pragma unroll
  for (int cc=0;cc<2;cc++)
    #pragma unroll
    for (int d=0;d<2;d++) rot_pair(h[cc*2+d], h[4+cc*2+d], cy, sy);
  // Rctl† on partner column (self-contained on (a,cc))
  {
    cplx t00=X[0], t11=X[3];
    X[0]=lc(n1a.A,t00, n1a.B,t11);
    X[3]=lc(n1a.D,t00, n1a.E,t11);
    X[1]=cmul(p,X[1]); X[2]=cmul(pc,X[2]);
    rot_pair(X[0],X[1],cy,sy); rot_pair(X[2],X[3],cy,sy);
    rot_pair(X[0],X[2],cy,sy); rot_pair(X[1],X[3],cy,sy);
  }
  // N2t† across the pair (coeffs preselected by bsel)
  #pragma unroll
  for (int j=0;j<4;j++){
    h[2*j]   = lc(al, h[2*j],   be, X[j]);
    h[2*j+1] = lc(ga, h[2*j+1], de, X[j]);
  }
  // N2c† on (a,cc) per d (self-contained)
  #pragma unroll
  for (int d=0;d<2;d++){
    cplx t00=h[d], t11=h[6+d];
    h[d]   = lc(n2a.A,t00, n2a.B,t11);
    h[6+d] = lc(n2a.D,t00, n2a.E,t11);
    h[2+d] = sc(n2a.C, h[2+d]);
    h[4+d] = sc(n2a.C, h[4+d]);
  }
  // scatter with CNOT fold
  #pragma unroll
  for (int i=0;i<8;i++){
    int a=(i>>2)&1, cc=(i>>1)&1, d=i&1;
    slab[bp ^ (a?KA:0) ^ ((bsel^a)?KB:0) ^ (cc?KC:0) ^ ((d^cc)?KD:0)] = h[i];
  }
}

// ---------------- R7 stage: full-16 duplicate compute, write own half ----------------
template<int U>
__device__ __forceinline__ void astage_r7full(cplx* __restrict__ slab, float4 rc, float4 rc7,
                                              int bp, int bsel, N1C n1a, N1C n2a){
  constexpr int KA=KPc(6+U), KB=KPc(5+U), KC=1<<U, KD=1<<(U-1);
  cplx h[16];
  #pragma unroll
  for (int idx=0; idx<16; idx++){
    int a=(idx>>3)&1, b=(idx>>2)&1, cc=(idx>>1)&1, d=idx&1;
    h[idx] = slab[bp ^ (a?KA:0) ^ (b?KB:0) ^ (cc?KC:0) ^ (d?KD:0)];
  }
  // R7† on (b,d)
  {
    cplx p=make_float2(rc7.z,-rc7.w), pc=make_float2(rc7.z,rc7.w);
    #pragma unroll
    for (int a=0;a<2;a++)
      #pragma unroll
      for (int cc=0;cc<2;cc++){
        int i=(a<<3)|(cc<<1);
        cplx t00=h[i], t11=h[i|5];
        h[i]   = lc(n1a.A,t00, n1a.B,t11);
        h[i|5] = lc(n1a.D,t00, n1a.E,t11);
        h[i|1] = cmul(p,  h[i|1]);
        h[i|4] = cmul(pc, h[i|4]);
      }
    float cy=rc7.x, sy=-rc7.y;
    #pragma unroll
    for (int a=0;a<2;a++)
      #pragma unroll
      for (int b=0;b<2;b++)
        #pragma unroll
        for (int cc=0;cc<2;cc++){
          int i=(a<<3)|(b<<2)|(cc<<1);
          rot_pair(h[i], h[i|1], cy, sy);
        }
    #pragma unroll
    for (int a=0;a<2;a++)
      #pragma unroll
      for (int cc=0;cc<2;cc++)
        #pragma unroll
        for (int d=0;d<2;d++){
          int i=(a<<3)|(cc<<1)|d;
          rot_pair(h[i], h[i|4], cy, sy);
        }
  }
  // Rctl† on (a,cc)
  {
    cplx p=make_float2(rc.z,-rc.w), pc=make_float2(rc.z,rc.w);
    #pragma unroll
    for (int b=0;b<2;b++)
      #pragma unroll
      for (int d=0;d<2;d++){
        int i=(b<<2)|d;
        cplx t00=h[i], t11=h[i|10];
        h[i]    = lc(n1a.A,t00, n1a.B,t11);
        h[i|10] = lc(n1a.D,t00, n1a.E,t11);
        h[i|2]  = cmul(p,  h[i|2]);
        h[i|8]  = cmul(pc, h[i|8]);
      }
    float cy=rc.x, sy=-rc.y;
    #pragma unroll
    for (int a=0;a<2;a++)
      #pragma unroll
      for (int b=0;b<2;b++)
        #pragma unroll
        for (int d=0;d<2;d++){
          int i=(a<<3)|(b<<2)|d;
          rot_pair(h[i], h[i|2], cy, sy);
        }
    #pragma unroll
    for (int b=0;b<2;b++)
      #pragma unroll
      for (int cc=0;cc<2;cc++)
        #pragma unroll
        for (int d=0;d<2;d++){
          int i=(b<<2)|(cc<<1)|d;
          rot_pair(h[i], h[i|8], cy, sy);
        }
  }
  // N2t† on (b,d)
  #pragma unroll
  for (int a=0;a<2;a++)
    #pragma unroll
    for (int cc=0;cc<2;cc++){
      int i=(a<<3)|(cc<<1);
      cplx t00=h[i], t11=h[i|5];
      h[i]   = lc(n2a.A,t00, n2a.B,t11);
      h[i|5] = lc(n2a.D,t00, n2a.E,t11);
      h[i|1] = sc(n2a.C, h[i|1]);
      h[i|4] = sc(n2a.C, h[i|4]);
    }
  // N2c† on (a,cc)
  #pragma unroll
  for (int b=0;b<2;b++)
    #pragma unroll
    for (int d=0;d<2;d++){
      int i=(b<<2)|d;
      cplx t00=h[i], t11=h[i|10];
      h[i]    = lc(n2a.A,t00, n2a.B,t11);
      h[i|10] = lc(n2a.D,t00, n2a.E,t11);
      h[i|2]  = sc(n2a.C, h[i|2]);
      h[i|8]  = sc(n2a.C, h[i|8]);
    }
  // scatter own half with CNOT fold
  #pragma unroll
  for (int idx=0; idx<16; idx++){
    int a=(idx>>3)&1, b=(idx>>2)&1, cc=(idx>>1)&1, d=idx&1;
    if (b == bsel)
      slab[bp ^ (a?KA:0) ^ ((b^a)?KB:0) ^ (cc?KC:0) ^ ((d^cc)?KD:0)] = h[idx];
  }
}

#define ASTG(l,q,u)  astage_half<u>(slab, sS[(l)*8+(q)], b##u, bsel, n1a, n2a, al,be,ga,de); __syncthreads();
#define ASTG7(l,q,u) astage_r7full<u>(slab, sS[(l)*8+(q)], sS[(l)*8+7], b##u, bsel, n1a, n2a); __syncthreads();

#define BSETUP512 \
  int t = threadIdx.x; int bsel = t & 1; int gg = t >> 1; \
  N1C n1a = mkadj(noise_coeffs(0.0003f)); \
  N1C n2a = mkadj(noise_coeffs(0.0065f)); \
  float al = bsel ? n2a.C : n2a.A; \
  float be = bsel ? 0.f   : n2a.B; \
  float ga = bsel ? n2a.E : n2a.C; \
  float de = bsel ? n2a.D : 0.f; \
  int b1=base_for<1>(gg), b2=base_for<2>(gg), b3=base_for<3>(gg), \
      b4=base_for<4>(gg), b5=base_for<5>(gg); \
  (void)b1;(void)b2;(void)b3;(void)b4;(void)b5;

#define MAKE_SS \
  if (t < 48){ \
    N1C n1 = noise_coeffs(0.0003f); \
    float w0=w[t*2], w1=w[t*2+1]; \
    sS[t] = make_float4(cosf(0.5f*w0), sinf(0.5f*w0), n1.C*cosf(w1), -n1.C*sinf(w1)); \
  }

// ---------------- bD: 4 diagonal W1 tiles, Z0 init, 5 stages ----------------
__global__ __launch_bounds__(512) void bD_kernel(const float* __restrict__ w,
                                                 cplx* __restrict__ gout,
                                                 float* __restrict__ out){
  __shared__ cplx slab[4096];
  __shared__ float4 sS[48];
  BSETUP512
  int oB = blockIdx.x * 5;           // diagonal tiles 0,5,10,15
  if (blockIdx.x==0 && t<BATCH) out[t] = 0.f;
  MAKE_SS
  float sgn = ((oB>>2)&2) ? -1.f : 1.f;   // qubit0 = r bit7 = r67 bit1
  #pragma unroll
  for (int k=0;k<8;k++){
    int L=(k<<9)|t, rl=L>>6, cl=L&63;
    slab[physof(L)] = make_float2((rl==cl)?sgn:0.f, 0.f);
  }
  __syncthreads();
  ASTG7(5,6,1) ASTG(5,5,2) ASTG(5,4,3) ASTG7(4,6,1) ASTG(4,5,2)
  cplx* go = gout + oB*4096;
  #pragma unroll
  for (int k=0;k<8;k++){ int L=(k<<9)|t; go[L]=slab[physof(L)]; }
}

// ---------------- bC: W2 window, reads W1 (only diag tiles nonzero), 8 stages ----------------
__global__ __launch_bounds__(512) void bC_kernel(const float* __restrict__ w,
                                                 const cplx* __restrict__ gin,
                                                 cplx* __restrict__ gout){
  __shared__ cplx slab[4096];
  __shared__ float4 sS[48];
  BSETUP512
  int oC=blockIdx.x, oCr=oC>>2, oCc=oC&3;
  MAKE_SS
  #pragma unroll
  for (int j=0;j<8;j++){
    int f=(j<<9)|t, mI=f>>8, told=f&255;
    int xx=told>>4, y=told&15;
    cplx v = ((mI>>2)==(mI&3))
           ? gin[mI*4096 + (((xx<<2)|oCr)<<6) + ((y<<2)|oCc)]
           : make_float2(0.f,0.f);
    int rlC=((mI>>2)<<4)|xx, clC=((mI&3)<<4)|y;
    slab[physof((rlC<<6)|clC)] = v;
  }
  __syncthreads();
  ASTG(5,3,2) ASTG(5,2,3) ASTG(5,1,4) ASTG(5,0,5)
  ASTG(4,4,1) ASTG(4,3,2) ASTG(4,2,3) ASTG(4,1,4)
  cplx* go = gout + oC*4096;
  #pragma unroll
  for (int k=0;k<8;k++){ int L=(k<<9)|t; go[L]=slab[physof(L)]; }
}

// ---------------- bB: W1 window, reads W2, 14 stages ----------------
__global__ __launch_bounds__(512) void bB_kernel(const float* __restrict__ w,
                                                 const cplx* __restrict__ gin,
                                                 cplx* __restrict__ gout){
  __shared__ cplx slab[4096];
  __shared__ float4 sS[48];
  BSETUP512
  int oB=blockIdx.x, r67=oB>>2, c67=oB&3;
  MAKE_SS
  #pragma unroll
  for (int j=0;j<8;j++){
    int f=(j<<9)|t, mI=f>>8, told=f&255;
    cplx v = gin[mI*4096 + (((r67<<4)|(told>>4))<<6) + ((c67<<4)|(told&15))];
    int rlB=((told>>4)<<2)|(mI>>2), clB=((told&15)<<2)|(mI&3);
    slab[physof((rlB<<6)|clB)] = v;
  }
  __syncthreads();
  ASTG7(3,6,1) ASTG(3,5,2) ASTG(3,4,3) ASTG(3,3,4) ASTG(3,2,5)
  ASTG7(2,6,1) ASTG(2,5,2) ASTG(2,4,3) ASTG(2,3,4)
  ASTG7(1,6,1) ASTG(1,5,2) ASTG(1,4,3)
  ASTG7(0,6,1) ASTG(0,5,2)
  cplx* go = gout + oB*4096;
  #pragma unroll
  for (int k=0;k<8;k++){ int L=(k<<9)|t; go[L]=slab[physof(L)]; }
}

// ---------------- bA: W2 window, reads W1, 15 stages ----------------
__global__ __launch_bounds__(512) void bA_kernel(const float* __restrict__ w,
                                                 const cplx* __restrict__ gin,
                                                 cplx* __restrict__ gout){
  __shared__ cplx slab[4096];
  __shared__ float4 sS[48];
  BSETUP512
  int oC=blockIdx.x, oCr=oC>>2, oCc=oC&3;
  MAKE_SS
  #pragma unroll
  for (int j=0;j<8;j++){
    int f=(j<<9)|t, mI=f>>8, told=f&255;
    int xx=told>>4, y=told&15;
    cplx v = gin[mI*4096 + (((xx<<2)|oCr)<<6) + ((y<<2)|oCc)];
    int rlC=((mI>>2)<<4)|xx, clC=((mI&3)<<4)|y;
    slab[physof((rlC<<6)|clC)] = v;
  }
  __syncthreads();
  ASTG(4,0,5)
  ASTG(3,1,4) ASTG(3,0,5)
  ASTG(2,2,3) ASTG(2,1,4) ASTG(2,0,5)
  ASTG(1,3,2) ASTG(1,2,3) ASTG(1,1,4) ASTG(1,0,5)
  ASTG(0,4,1) ASTG(0,3,2) ASTG(0,2,3) ASTG(0,1,4) ASTG(0,0,5)
  cplx* go = gout + oC*4096;
  #pragma unroll
  for (int k=0;k<8;k++){ int L=(k<<9)|t; go[L]=slab[physof(L)]; }
}

// ---------------- expect: 4 blocks/sample, m inline, atomicAdd ----------------
// O in W2 layout: f = o*4096 + rl*64 + cl, r=(rl<<2)|(o>>2), c=(cl<<2)|(o&3)
__global__ __launch_bounds__(256) void expect_kernel(const cplx* __restrict__ O,
                                                     const float* __restrict__ x,
                                                     float* __restrict__ out){
  __shared__ float sm[32];
  __shared__ float red[4];
  int t = threadIdx.x;
  int s = blockIdx.x>>2, oq = blockIdx.x&3;
  if (t<8){
    N1C n1 = noise_coeffs(0.0003f);
    float xv = x[s*8+t];
    float c = cosf(0.5f*xv), sn = sinf(0.5f*xv);
    float p00=c*c, p01=c*sn, p11=sn*sn;
    sm[t*4+0]=n1.A*p00+n1.B*p11; sm[t*4+1]=n1.C*p01;
    sm[t*4+2]=n1.C*p01;          sm[t*4+3]=n1.D*p00+n1.E*p11;
  }
  __syncthreads();
  int cl = t & 63;
  float p0[2],p1[2],p2[2],p3[2];
  float wbase;
  {
    float q4a = sm[16 + 0 + ((cl>>1)&1)], q4b = sm[16 + 2 + ((cl>>1)&1)];
    float q5a = sm[20 + 0 + (cl&1)],      q5b = sm[20 + 2 + (cl&1)];
    int r32 = t>>6;
    float w4 = (r32>>1) ? q4b : q4a;
    float w5 = (r32&1)  ? q5b : q5a;
    wbase = w4 * w5;
    int c0=(cl>>5)&1, c1=(cl>>4)&1, c2=(cl>>3)&1, c3=(cl>>2)&1;
    p0[0]=sm[0+c0];  p0[1]=sm[2+c0];
    p1[0]=sm[4+c1];  p1[1]=sm[6+c1];
    p2[0]=sm[8+c2];  p2[1]=sm[10+c2];
    p3[0]=sm[12+c3]; p3[1]=sm[14+c3];
  }
  float acc = 0.f;
  #pragma unroll
  for (int oo=0;oo<4;oo++){
    int o = (oq<<2)|oo;
    int r6=(o>>3)&1, r7=(o>>2)&1, c6=(o>>1)&1, c7=o&1;
    float w67 = sm[24 + r6*2 + c6] * sm[28 + r7*2 + c7] * wbase;
    const cplx* Op = O + (o<<12) + t;
    #pragma unroll
    for (int rh=0; rh<16; rh++){
      float w = w67 * p0[(rh>>3)&1] * p1[(rh>>2)&1] * p2[(rh>>1)&1] * p3[rh&1];
      acc += Op[rh<<8].x * w;
    }
  }
  #pragma unroll
  for (int off=32;off>0;off>>=1) acc += __shfl_down(acc, off, 64);
  if ((t&63)==0) red[t>>6]=acc;
  __syncthreads();
  if (t==0) atomicAdd(&out[s], red[0]+red[1]+red[2]+red[3]);
}

extern "C" void kernel_launch(void* const* d_in, const int* in_sizes, int n_in,
                              void* d_out, int out_size, void* d_ws, size_t ws_size,
                              hipStream_t stream) {
  const float* x = (const float*)d_in[0];   // [32,8]
  const float* w = (const float*)d_in[1];   // [6,8,2]
  float* out = (float*)d_out;               // [32,1] f32
  char* ws = (char*)d_ws;

  cplx* buf0 = (cplx*)ws;                       // 512 KB (W1 layout)
  cplx* buf1 = (cplx*)(ws + (size_t)1048576);   // 512 KB (W2 layout)

  bD_kernel<<<4, 512, 0, stream>>>(w, buf0, out);
  bC_kernel<<<16, 512, 0, stream>>>(w, buf0, buf1);
  bB_kernel<<<16, 512, 0, stream>>>(w, buf1, buf0);
  bA_kernel<<<16, 512, 0, stream>>>(w, buf0, buf1);
  expect_kernel<<<BATCH*4, 256, 0, stream>>>(buf1, x, out);
}